// Round 4
// baseline (225.537 us; speedup 1.0000x reference)
//
#include <hip/hip_runtime.h>
#include <math.h>

// Problem constants (fixed by setup_inputs)
#define BATCH 8
#define CH    256
#define H     128
#define W     128
#define PLANE (H * W)            // 16384
#define NPIX  (BATCH * PLANE)    // 131072
#define NSHIFT 12                // symmetric half of the 24 shifts
#define NMAPS  13                // 12 shifted dots + normsq
#define NCHUNK 4                 // channel chunks
#define CPC    (CH / NCHUNK)     // 64 channels per chunk
#define CSTRIDE (NMAPS * NPIX)   // floats per chunk slice (1703936)

// 12 "positive" shifts: dy>0 or (dy==0 && dx>0). Negatives recovered by symmetry.
static __device__ __constant__ int S_DY[NSHIFT] = {0,0,1,1,1,1,1,2,2,2,2,2};
static __device__ __constant__ int S_DX[NSHIFT] = {1,2,-2,-1,0,1,2,-2,-1,0,1,2};

// R4: back to the R2-winning geometry (8-row tiles, 512-thread blocks,
// 2 blocks/CU — R3's 1024-thr/1-block-per-CU retile regressed +7.7 us:
// 16-wave barrier drain with no co-resident block to hide it).
#define TROWS  8
#define SROWS  (TROWS + 2)                       // 10 staged rows
#define NTILE  (H / TROWS)                       // 16
#define NCORRB (BATCH * NTILE * NCHUNK)          // 512 corr blocks (2/CU)
#define NLOSSB (NPIX / 256)                      // 512 loss blocks

__device__ __forceinline__ void fma4(float& acc, const float4& a, const float4& b) {
    acc = fmaf(a.x, b.x, acc);
    acc = fmaf(a.y, b.y, acc);
    acc = fmaf(a.z, b.z, acc);
    acc = fmaf(a.w, b.w, acc);
}

// ---------------------------------------------------------------------------
// Kernel C: pure correlation. Grid decode: chunk(4) | tile(16) | b(8).
//   512 thr; each thread computes 2 adjacent output rows (block covers 8
//   rows, stages 10 rows x 4 channels as float4-per-pixel in LDS; 0 bank
//   conflicts measured for this read pattern).
//   Double-buffered LDS: ONE barrier per channel-quad. Depth-2 register
//   prefetch: quad k+2's global loads issue during quad k's compute.
//   Block 0 additionally zeroes the tiny stats/ticket globals (stream
//   ordering makes them visible to k_loss) — replaces the k_prep launch.
// __launch_bounds__(512,4): 8 waves/block, 2 blocks/CU, 128-VGPR budget.
// ---------------------------------------------------------------------------
__global__ __launch_bounds__(512, 4) void k_corr(const float* __restrict__ er,
                                                 float* __restrict__ comb,
                                                 int* __restrict__ cnt,
                                                 int* __restrict__ inc,
                                                 float* __restrict__ tot,
                                                 unsigned int* __restrict__ done) {
    __shared__ float4 lds[2][SROWS][132];   // 2 buffers, 10 rows, x padded 2/side
    int t = threadIdx.x;

    // block 0: init the tiny globals (consumed only by k_loss, next kernel)
    if (blockIdx.x == 0) {
        if (t < 8)               cnt[t] = 0;
        else if (t < 16)         inc[t - 8] = 0;
        else if (t < 24)         tot[t - 16] = 0.0f;
        else if (t == 24)        *done = 0u;
    }

    int blk = blockIdx.x;
    int chunk = blk & 3;
    int tile  = (blk >> 2) & 15;
    int b     = blk >> 6;
    int y0 = tile * TROWS;           // block covers output rows y0..y0+7
    int c0 = chunk * CPC;
    int r = t >> 7;                  // thread handles output rows y0+2r, y0+2r+1
    int x = t & 127;

    // zero the x-pad slots of BOTH buffers once (first barrier makes visible)
    if (t >= 128 && t < 128 + 2 * SROWS * 4) {   // 80 threads, away from init path
        int u = t - 128;
        int bi = u / (SROWS * 4), rem = u % (SROWS * 4);
        int row = rem >> 2, col = rem & 3;
        int xs = (col < 2) ? col : (col + 128);   // 0,1,130,131
        lds[bi][row][xs] = make_float4(0.f, 0.f, 0.f, 0.f);
    }

    float accA[13], accB[13];
#pragma unroll
    for (int i = 0; i < 13; i++) { accA[i] = 0.0f; accB[i] = 0.0f; }

    const float* base = er + (size_t)b * CH * PLANE;

    // prefetch registers: up to 3 stage slots x 4 channels (slot 2: t<256 only;
    // staged px = 10*128 = 1280 = 2.5 * 512)
    float pf[3][4];
    auto load_quad = [&](int c) {
#pragma unroll
        for (int k = 0; k < 3; ++k) {
            if (k < 2 || t < 256) {
                int s = t + k * 512;         // 0..1279
                int row = s >> 7;            // 0..9
                int xs = s & 127;
                int y = y0 + row;
                if (y < H) {
                    const float* p0 = base + (size_t)c * PLANE + y * W + xs;
                    pf[k][0] = p0[0];
                    pf[k][1] = p0[PLANE];
                    pf[k][2] = p0[2 * PLANE];
                    pf[k][3] = p0[3 * PLANE];
                } else {
                    pf[k][0] = 0.f; pf[k][1] = 0.f; pf[k][2] = 0.f; pf[k][3] = 0.f;
                }
            }
        }
    };
    auto commit_quad = [&](int bi) {
#pragma unroll
        for (int k = 0; k < 3; ++k) {
            if (k < 2 || t < 256) {
                int s = t + k * 512;
                int row = s >> 7;
                int xs = s & 127;
                lds[bi][row][xs + 2] = make_float4(pf[k][0], pf[k][1], pf[k][2], pf[k][3]);
            }
        }
    };

    const int iters = CPC / 4;       // 16
    // prologue: quad 0 -> buf0; quad 1 in flight
    load_quad(c0);
    commit_quad(0);
    load_quad(c0 + 4);

    auto iter = [&](int it, int cur) {
        __syncthreads();   // buf[cur] writes visible; buf[cur^1] reads (prev iter) done
        if (it + 1 < iters) commit_quad(cur ^ 1);          // vmcnt wait lands here
        if (it + 2 < iters) load_quad(c0 + 4 * (it + 2));  // overlaps compute below

        const float4* lp = &lds[cur][2 * r][x + 2];
        float4 cA = lp[0];               // (rel row 0, dx 0)
        float4 cB = lp[132];             // (rel row 1, dx 0)
        // rel row 0: dx {0,1,2} -> accA[0..2]
        {
            float4 v1 = lp[1], v2 = lp[2];
            fma4(accA[0], cA, cA);
            fma4(accA[1], cA, v1);
            fma4(accA[2], cA, v2);
        }
        // rel row 1: dx {-2..2} -> accA[3..7]; accB[0..2] (dx 0,1,2)
        {
            float4 m2 = lp[130], m1 = lp[131], p1 = lp[133], p2 = lp[134];
            fma4(accA[3], cA, m2);
            fma4(accA[4], cA, m1);
            fma4(accA[5], cA, cB);
            fma4(accA[6], cA, p1);
            fma4(accA[7], cA, p2);
            fma4(accB[0], cB, cB);
            fma4(accB[1], cB, p1);
            fma4(accB[2], cB, p2);
        }
        // rel row 2: dx {-2..2} -> accA[8..12]; accB[3..7]
        {
            float4 m2 = lp[262], m1 = lp[263], v0 = lp[264], p1 = lp[265], p2 = lp[266];
            fma4(accA[8],  cA, m2);
            fma4(accA[9],  cA, m1);
            fma4(accA[10], cA, v0);
            fma4(accA[11], cA, p1);
            fma4(accA[12], cA, p2);
            fma4(accB[3], cB, m2);
            fma4(accB[4], cB, m1);
            fma4(accB[5], cB, v0);
            fma4(accB[6], cB, p1);
            fma4(accB[7], cB, p2);
        }
        // rel row 3: dx {-2..2} -> accB[8..12]
        {
            float4 m2 = lp[394], m1 = lp[395], v0 = lp[396], p1 = lp[397], p2 = lp[398];
            fma4(accB[8],  cB, m2);
            fma4(accB[9],  cB, m1);
            fma4(accB[10], cB, v0);
            fma4(accB[11], cB, p1);
            fma4(accB[12], cB, p2);
        }
    };

    for (int it = 0; it < iters; it += 2) {
        iter(it, 0);
        iter(it + 1, 1);
    }

    // plain coalesced stores into this chunk's private slice
    float* cb = comb + (size_t)chunk * CSTRIDE;
    int pixA = b * PLANE + (y0 + 2 * r) * W + x;
    int pixB = pixA + W;
#pragma unroll
    for (int m = 0; m < NSHIFT; ++m) {
        cb[m * NPIX + pixA] = accA[m + 1];
        cb[m * NPIX + pixB] = accB[m + 1];
    }
    cb[NSHIFT * NPIX + pixA] = accA[0];
    cb[NSHIFT * NPIX + pixB] = accB[0];
}

// ---------------------------------------------------------------------------
// Kernel R: per-pixel reciprocal norm = 1/max(sqrt(sum_c normsq), 1e-8).
// ---------------------------------------------------------------------------
__global__ __launch_bounds__(256) void k_rn(const float* __restrict__ comb,
                                            float* __restrict__ rn) {
    int idx = blockIdx.x * 256 + threadIdx.x;
    const float* ns = comb + NSHIFT * NPIX;
    float s = (ns[idx] + ns[idx + CSTRIDE]) + (ns[idx + 2 * CSTRIDE] + ns[idx + 3 * CSTRIDE]);
    rn[idx] = fminf(rsqrtf(s), 1e8f);   // s==0 -> inf -> clamp = 1/1e-8
}

// ---------------------------------------------------------------------------
// Kernel L: per-valid-pixel loss assembly + per-image stats + final
// normalization (last-block ticket replaces the k_fin launch).
// comb layout: [chunk][map][pix]; maps 0..11 = shifted dots, 12 = normsq.
// ---------------------------------------------------------------------------
__device__ __forceinline__ float sum4c(const float* __restrict__ p) {
    return (p[0] + p[CSTRIDE]) + (p[2 * CSTRIDE] + p[3 * CSTRIDE]);
}

__global__ __launch_bounds__(256) void k_loss(const float* __restrict__ comb,
                                              const float* __restrict__ rn,
                                              const int* __restrict__ seg,
                                              const int* __restrict__ gtb,
                                              int* __restrict__ cnt,
                                              int* __restrict__ inc,
                                              float* __restrict__ tot,
                                              unsigned int* __restrict__ done,
                                              float* __restrict__ out) {
    const float* dots = comb;                  // + i*NPIX per map (chunk 0 slice)
    int idx = blockIdx.x * 256 + threadIdx.x;
    int b = idx >> 14;                         // uniform per block (64 blocks/image)
    int rem = idx & (PLANE - 1);
    int y = rem >> 7;
    int x = rem & 127;

    float val = 0.0f;
    int my_cnt = 0, my_any = 0;
    {
        int sp = seg[idx];
        int gp = gtb[idx];
        int s0 = (sp == 255) ? 0 : sp;
        int g0 = (gp == 255) ? 0 : gp;
        if (s0 > 0 && g0 > 0) {
            my_any = 1;
            if (y >= 2 && y < H - 2 && x >= 2 && x < W - 2) {
                my_cnt = 1;
                float npr = rn[idx];
                float sum = 0.0f;
#pragma unroll
                for (int i = 0; i < NSHIFT; ++i) {
                    int off = S_DY[i] * W + S_DX[i];
                    // + shift: cos(p, p+d)
                    {
                        float d  = sum4c(dots + i * NPIX + idx);
                        float cosv = d * (npr * rn[idx + off]);
                        int sq = seg[idx + off];
                        float lab = (sp == sq && sp < 2) ? 1.0f : 0.0f;
                        float tt = cosv - lab;
                        sum = fmaf(tt, tt, sum);
                    }
                    // - shift: cos(p, p-d) = dot_d(p-d)/(norm(p)norm(p-d))
                    {
                        float d  = sum4c(dots + i * NPIX + idx - off);
                        float cosv = d * (npr * rn[idx - off]);
                        int sq = seg[idx - off];
                        float lab = (sp == sq && sp < 2) ? 1.0f : 0.0f;
                        float tt = cosv - lab;
                        sum = fmaf(tt, tt, sum);
                    }
                }
                val = sum;
            }
        }
    }

    // block reduction: wave shuffle then LDS across 4 waves
    for (int o = 32; o > 0; o >>= 1) {
        val    += __shfl_down(val, o, 64);
        my_cnt += __shfl_down(my_cnt, o, 64);
        my_any |= __shfl_down(my_any, o, 64);
    }
    __shared__ float wsum[4];
    __shared__ int wc[4], wa[4];
    int lane = threadIdx.x & 63;
    int wid  = threadIdx.x >> 6;
    if (lane == 0) { wsum[wid] = val; wc[wid] = my_cnt; wa[wid] = my_any; }
    __syncthreads();
    if (threadIdx.x == 0) {
        float s = wsum[0] + wsum[1] + wsum[2] + wsum[3];
        int c = wc[0] + wc[1] + wc[2] + wc[3];
        int a = wa[0] | wa[1] | wa[2] | wa[3];
        if (s != 0.0f) atomicAdd(&tot[b], s);
        if (c) atomicAdd(&cnt[b], c);
        if (a) atomicOr(&inc[b], 1);
        __threadfence();                       // release our contributions
        unsigned int old = atomicAdd(done, 1u);
        if (old == NLOSSB - 1) {
            __threadfence();                   // acquire all contributions
            int sn = 0;
            float fs = 0.0f;
#pragma unroll
            for (int b2 = 0; b2 < BATCH; ++b2) {
                int ib = inc[b2];
                sn += (ib != 0);
                int cb = cnt[b2]; if (cb < 1) cb = 1;
                if (ib) fs += tot[b2] / (24.0f * (float)cb);
            }
            if (sn < 1) sn = 1;
            out[0] = fs / (float)sn;
        }
    }
}

// ---------------------------------------------------------------------------
extern "C" void kernel_launch(void* const* d_in, const int* in_sizes, int n_in,
                              void* d_out, int out_size, void* d_ws, size_t ws_size,
                              hipStream_t stream) {
    const float* er  = (const float*)d_in[0];
    const int*   seg = (const int*)d_in[1];
    const int*   gtb = (const int*)d_in[2];
    float* out = (float*)d_out;

    float* ws   = (float*)d_ws;
    float* comb = ws;                                  // 4 * 13 * NPIX floats (27.3 MB)
    float* rn   = comb + NCHUNK * CSTRIDE;             // NPIX floats (0.5 MB)
    float* tot  = rn + NPIX;                           // 8 floats
    int*   cnt  = (int*)(tot + 8);                     // 8 ints
    int*   inc  = cnt + 8;                             // 8 ints
    unsigned int* done = (unsigned int*)(inc + 8);     // 1 uint

    hipLaunchKernelGGL(k_corr, dim3(NCORRB), dim3(512), 0, stream,
                       er, comb, cnt, inc, tot, done);
    hipLaunchKernelGGL(k_rn, dim3(NPIX / 256), dim3(256), 0, stream, comb, rn);
    hipLaunchKernelGGL(k_loss, dim3(NLOSSB), dim3(256), 0, stream,
                       comb, rn, seg, gtb, cnt, inc, tot, done, out);
}

// Round 5
// 223.071 us; speedup vs baseline: 1.0111x; 1.0111x over previous
//
#include <hip/hip_runtime.h>
#include <math.h>

// Problem constants (fixed by setup_inputs)
#define BATCH 8
#define CH    256
#define H     128
#define W     128
#define PLANE (H * W)            // 16384
#define NPIX  (BATCH * PLANE)    // 131072
#define NSHIFT 12                // symmetric half of the 24 shifts
#define NMAPS  13                // 12 shifted dots + normsq
#define NCHUNK 4                 // channel chunks
#define CPC    (CH / NCHUNK)     // 64 channels per chunk
#define CSTRIDE (NMAPS * NPIX)   // floats per chunk slice (1703936)

// 12 "positive" shifts: dy>0 or (dy==0 && dx>0). Negatives recovered by symmetry.
static __device__ __constant__ int S_DY[NSHIFT] = {0,0,1,1,1,1,1,2,2,2,2,2};
static __device__ __constant__ int S_DX[NSHIFT] = {1,2,-2,-1,0,1,2,-2,-1,0,1,2};

// R2-winning geometry: 8-row tiles, 512-thread blocks, 2 blocks/CU.
// (R3: 1024thr/1-block-per-CU regressed — no co-resident block to hide the
//  barrier drain. R4: last-block __threadfence ticket regressed ~10us — 512
//  device-scope fences = L2 wb/inv storm that killed k_loss cache locality.)
#define TROWS  8
#define SROWS  (TROWS + 2)                       // 10 staged rows
#define NTILE  (H / TROWS)                       // 16
#define NCORRB (BATCH * NTILE * NCHUNK)          // 512 corr blocks (2/CU)
#define NLOSSB (NPIX / 256)                      // 512 loss blocks

__device__ __forceinline__ void fma4(float& acc, const float4& a, const float4& b) {
    acc = fmaf(a.x, b.x, acc);
    acc = fmaf(a.y, b.y, acc);
    acc = fmaf(a.z, b.z, acc);
    acc = fmaf(a.w, b.w, acc);
}

// ---------------------------------------------------------------------------
// Kernel C: pure correlation. Grid decode: chunk(4) | tile(16) | b(8).
//   512 thr; each thread computes 2 adjacent output rows (block covers 8
//   rows, stages 10 rows x 4 channels as float4-per-pixel in LDS; 0 bank
//   conflicts measured for this read pattern).
//   Double-buffered LDS: ONE barrier per channel-quad. Depth-2 register
//   prefetch: quad k+2's global loads issue during quad k's compute.
//   Block 0 zeroes the tiny stats globals (stream order → visible to k_loss).
// __launch_bounds__(512,4): 8 waves/block, 2 blocks/CU, 128-VGPR budget.
// ---------------------------------------------------------------------------
__global__ __launch_bounds__(512, 4) void k_corr(const float* __restrict__ er,
                                                 float* __restrict__ comb,
                                                 int* __restrict__ cnt,
                                                 int* __restrict__ inc,
                                                 float* __restrict__ tot) {
    __shared__ float4 lds[2][SROWS][132];   // 2 buffers, 10 rows, x padded 2/side
    int t = threadIdx.x;

    // block 0: init the tiny globals (consumed only by k_loss, later kernel)
    if (blockIdx.x == 0) {
        if (t < 8)               cnt[t] = 0;
        else if (t < 16)         inc[t - 8] = 0;
        else if (t < 24)         tot[t - 16] = 0.0f;
    }

    int blk = blockIdx.x;
    int chunk = blk & 3;
    int tile  = (blk >> 2) & 15;
    int b     = blk >> 6;
    int y0 = tile * TROWS;           // block covers output rows y0..y0+7
    int c0 = chunk * CPC;
    int r = t >> 7;                  // thread handles output rows y0+2r, y0+2r+1
    int x = t & 127;

    // zero the x-pad slots of BOTH buffers once (first barrier makes visible)
    if (t >= 128 && t < 128 + 2 * SROWS * 4) {   // 80 threads, off the init path
        int u = t - 128;
        int bi = u / (SROWS * 4), rem = u % (SROWS * 4);
        int row = rem >> 2, col = rem & 3;
        int xs = (col < 2) ? col : (col + 128);   // 0,1,130,131
        lds[bi][row][xs] = make_float4(0.f, 0.f, 0.f, 0.f);
    }

    float accA[13], accB[13];
#pragma unroll
    for (int i = 0; i < 13; i++) { accA[i] = 0.0f; accB[i] = 0.0f; }

    const float* base = er + (size_t)b * CH * PLANE;

    // prefetch registers: up to 3 stage slots x 4 channels (slot 2: t<256 only;
    // staged px = 10*128 = 1280 = 2.5 * 512)
    float pf[3][4];
    auto load_quad = [&](int c) {
#pragma unroll
        for (int k = 0; k < 3; ++k) {
            if (k < 2 || t < 256) {
                int s = t + k * 512;         // 0..1279
                int row = s >> 7;            // 0..9
                int xs = s & 127;
                int y = y0 + row;
                if (y < H) {
                    const float* p0 = base + (size_t)c * PLANE + y * W + xs;
                    pf[k][0] = p0[0];
                    pf[k][1] = p0[PLANE];
                    pf[k][2] = p0[2 * PLANE];
                    pf[k][3] = p0[3 * PLANE];
                } else {
                    pf[k][0] = 0.f; pf[k][1] = 0.f; pf[k][2] = 0.f; pf[k][3] = 0.f;
                }
            }
        }
    };
    auto commit_quad = [&](int bi) {
#pragma unroll
        for (int k = 0; k < 3; ++k) {
            if (k < 2 || t < 256) {
                int s = t + k * 512;
                int row = s >> 7;
                int xs = s & 127;
                lds[bi][row][xs + 2] = make_float4(pf[k][0], pf[k][1], pf[k][2], pf[k][3]);
            }
        }
    };

    const int iters = CPC / 4;       // 16
    // prologue: quad 0 -> buf0; quad 1 in flight
    load_quad(c0);
    commit_quad(0);
    load_quad(c0 + 4);

    auto iter = [&](int it, int cur) {
        __syncthreads();   // buf[cur] writes visible; buf[cur^1] reads (prev iter) done
        if (it + 1 < iters) commit_quad(cur ^ 1);          // vmcnt wait lands here
        if (it + 2 < iters) load_quad(c0 + 4 * (it + 2));  // overlaps compute below

        const float4* lp = &lds[cur][2 * r][x + 2];
        float4 cA = lp[0];               // (rel row 0, dx 0)
        float4 cB = lp[132];             // (rel row 1, dx 0)
        // rel row 0: dx {0,1,2} -> accA[0..2]
        {
            float4 v1 = lp[1], v2 = lp[2];
            fma4(accA[0], cA, cA);
            fma4(accA[1], cA, v1);
            fma4(accA[2], cA, v2);
        }
        // rel row 1: dx {-2..2} -> accA[3..7]; accB[0..2] (dx 0,1,2)
        {
            float4 m2 = lp[130], m1 = lp[131], p1 = lp[133], p2 = lp[134];
            fma4(accA[3], cA, m2);
            fma4(accA[4], cA, m1);
            fma4(accA[5], cA, cB);
            fma4(accA[6], cA, p1);
            fma4(accA[7], cA, p2);
            fma4(accB[0], cB, cB);
            fma4(accB[1], cB, p1);
            fma4(accB[2], cB, p2);
        }
        // rel row 2: dx {-2..2} -> accA[8..12]; accB[3..7]
        {
            float4 m2 = lp[262], m1 = lp[263], v0 = lp[264], p1 = lp[265], p2 = lp[266];
            fma4(accA[8],  cA, m2);
            fma4(accA[9],  cA, m1);
            fma4(accA[10], cA, v0);
            fma4(accA[11], cA, p1);
            fma4(accA[12], cA, p2);
            fma4(accB[3], cB, m2);
            fma4(accB[4], cB, m1);
            fma4(accB[5], cB, v0);
            fma4(accB[6], cB, p1);
            fma4(accB[7], cB, p2);
        }
        // rel row 3: dx {-2..2} -> accB[8..12]
        {
            float4 m2 = lp[394], m1 = lp[395], v0 = lp[396], p1 = lp[397], p2 = lp[398];
            fma4(accB[8],  cB, m2);
            fma4(accB[9],  cB, m1);
            fma4(accB[10], cB, v0);
            fma4(accB[11], cB, p1);
            fma4(accB[12], cB, p2);
        }
    };

    for (int it = 0; it < iters; it += 2) {
        iter(it, 0);
        iter(it + 1, 1);
    }

    // plain coalesced stores into this chunk's private slice
    float* cb = comb + (size_t)chunk * CSTRIDE;
    int pixA = b * PLANE + (y0 + 2 * r) * W + x;
    int pixB = pixA + W;
#pragma unroll
    for (int m = 0; m < NSHIFT; ++m) {
        cb[m * NPIX + pixA] = accA[m + 1];
        cb[m * NPIX + pixB] = accB[m + 1];
    }
    cb[NSHIFT * NPIX + pixA] = accA[0];
    cb[NSHIFT * NPIX + pixB] = accB[0];
}

// ---------------------------------------------------------------------------
// Kernel R: chunk-fold. For all 13 maps, sum the 4 chunk slices:
//   maps 0..11 -> csum[map][pix]  (k_loss then does 1 load per dot, not 4)
//   map 12     -> rn[pix] = min(rsqrt(sum), 1e8)  (== 1/max(sqrt,1e-8))
// Streaming L3-resident traffic (~34 MB read, ~7 MB write).
// ---------------------------------------------------------------------------
__global__ __launch_bounds__(256) void k_rn(const float* __restrict__ comb,
                                            float* __restrict__ csum,
                                            float* __restrict__ rn) {
    int idx = blockIdx.x * 256 + threadIdx.x;   // 0 .. 13*NPIX-1
    int map = idx >> 17;                        // NPIX = 2^17
    const float* p = comb + idx;                // chunk-0 slice is [map][pix]
    float s = (p[0] + p[CSTRIDE]) + (p[2 * CSTRIDE] + p[3 * CSTRIDE]);
    if (map < NSHIFT) csum[idx] = s;
    else              rn[idx - NSHIFT * NPIX] = fminf(rsqrtf(s), 1e8f);
}

// ---------------------------------------------------------------------------
// Kernel L: per-valid-pixel loss assembly + per-image stats (raw sums only;
// normalization deferred to k_fin — no cross-kernel read dependency here,
// and NO device fences).
// ---------------------------------------------------------------------------
__global__ __launch_bounds__(256) void k_loss(const float* __restrict__ csum,
                                              const float* __restrict__ rn,
                                              const int* __restrict__ seg,
                                              const int* __restrict__ gtb,
                                              int* __restrict__ cnt,
                                              int* __restrict__ inc,
                                              float* __restrict__ tot) {
    int idx = blockIdx.x * 256 + threadIdx.x;
    int b = idx >> 14;                         // uniform per block (64 blocks/image)
    int rem = idx & (PLANE - 1);
    int y = rem >> 7;
    int x = rem & 127;

    float val = 0.0f;
    int my_cnt = 0, my_any = 0;
    {
        int sp = seg[idx];
        int gp = gtb[idx];
        int s0 = (sp == 255) ? 0 : sp;
        int g0 = (gp == 255) ? 0 : gp;
        if (s0 > 0 && g0 > 0) {
            my_any = 1;
            if (y >= 2 && y < H - 2 && x >= 2 && x < W - 2) {
                my_cnt = 1;
                float npr = rn[idx];
                float sum = 0.0f;
#pragma unroll
                for (int i = 0; i < NSHIFT; ++i) {
                    int off = S_DY[i] * W + S_DX[i];
                    // + shift: cos(p, p+d)
                    {
                        float d  = csum[i * NPIX + idx];
                        float cosv = d * (npr * rn[idx + off]);
                        int sq = seg[idx + off];
                        float lab = (sp == sq && sp < 2) ? 1.0f : 0.0f;
                        float tt = cosv - lab;
                        sum = fmaf(tt, tt, sum);
                    }
                    // - shift: cos(p, p-d) = dot_d(p-d)/(norm(p)norm(p-d))
                    {
                        float d  = csum[i * NPIX + idx - off];
                        float cosv = d * (npr * rn[idx - off]);
                        int sq = seg[idx - off];
                        float lab = (sp == sq && sp < 2) ? 1.0f : 0.0f;
                        float tt = cosv - lab;
                        sum = fmaf(tt, tt, sum);
                    }
                }
                val = sum;
            }
        }
    }

    // block reduction: wave shuffle then LDS across 4 waves
    for (int o = 32; o > 0; o >>= 1) {
        val    += __shfl_down(val, o, 64);
        my_cnt += __shfl_down(my_cnt, o, 64);
        my_any |= __shfl_down(my_any, o, 64);
    }
    __shared__ float wsum[4];
    __shared__ int wc[4], wa[4];
    int lane = threadIdx.x & 63;
    int wid  = threadIdx.x >> 6;
    if (lane == 0) { wsum[wid] = val; wc[wid] = my_cnt; wa[wid] = my_any; }
    __syncthreads();
    if (threadIdx.x == 0) {
        float s = wsum[0] + wsum[1] + wsum[2] + wsum[3];
        int c = wc[0] + wc[1] + wc[2] + wc[3];
        int a = wa[0] | wa[1] | wa[2] | wa[3];
        if (s != 0.0f) atomicAdd(&tot[b], s);
        if (c) atomicAdd(&cnt[b], c);
        if (a) atomicOr(&inc[b], 1);
    }
}

// ---------------------------------------------------------------------------
// Kernel F: final normalization (1 block; atomics above are device-visible
// to a later kernel launch on the same stream).
// out = ( sum_b inc_b ? tot_b / (24 * max(cnt_b,1)) : 0 ) / max(sum inc_b, 1)
// ---------------------------------------------------------------------------
__global__ __launch_bounds__(64) void k_fin(const int* __restrict__ cnt,
                                            const int* __restrict__ inc,
                                            const float* __restrict__ tot,
                                            float* __restrict__ out) {
    if (threadIdx.x == 0) {
        int sn = 0;
        float s = 0.0f;
#pragma unroll
        for (int b = 0; b < BATCH; ++b) {
            int ib = inc[b];
            sn += (ib != 0);
            int cb = cnt[b]; if (cb < 1) cb = 1;
            if (ib) s += tot[b] / (24.0f * (float)cb);
        }
        if (sn < 1) sn = 1;
        out[0] = s / (float)sn;
    }
}

// ---------------------------------------------------------------------------
extern "C" void kernel_launch(void* const* d_in, const int* in_sizes, int n_in,
                              void* d_out, int out_size, void* d_ws, size_t ws_size,
                              hipStream_t stream) {
    const float* er  = (const float*)d_in[0];
    const int*   seg = (const int*)d_in[1];
    const int*   gtb = (const int*)d_in[2];
    float* out = (float*)d_out;

    float* ws   = (float*)d_ws;
    float* comb = ws;                                  // 4 * 13 * NPIX floats (27.3 MB)
    float* csum = comb + NCHUNK * CSTRIDE;             // 12 * NPIX floats (6.3 MB)
    float* rn   = csum + NSHIFT * NPIX;                // NPIX floats (0.5 MB)
    float* tot  = rn + NPIX;                           // 8 floats
    int*   cnt  = (int*)(tot + 8);                     // 8 ints
    int*   inc  = cnt + 8;                             // 8 ints

    hipLaunchKernelGGL(k_corr, dim3(NCORRB), dim3(512), 0, stream,
                       er, comb, cnt, inc, tot);
    hipLaunchKernelGGL(k_rn, dim3(NMAPS * NPIX / 256), dim3(256), 0, stream,
                       comb, csum, rn);
    hipLaunchKernelGGL(k_loss, dim3(NLOSSB), dim3(256), 0, stream,
                       csum, rn, seg, gtb, cnt, inc, tot);
    hipLaunchKernelGGL(k_fin, dim3(1), dim3(64), 0, stream, cnt, inc, tot, out);
}

// Round 7
// 222.787 us; speedup vs baseline: 1.0123x; 1.0013x over previous
//
#include <hip/hip_runtime.h>
#include <math.h>

// Problem constants (fixed by setup_inputs)
#define BATCH 8
#define CH    256
#define H     128
#define W     128
#define PLANE (H * W)            // 16384
#define NPIX  (BATCH * PLANE)    // 131072
#define NSHIFT 12                // symmetric half of the 24 shifts
#define NMAPS  13                // 12 shifted dots + normsq
#define NCHUNK 4                 // channel chunks
#define CPC    (CH / NCHUNK)     // 64 channels per chunk
#define CSTRIDE (NMAPS * NPIX)   // floats per chunk slice (1703936)

// 12 "positive" shifts: dy>0 or (dy==0 && dx>0). Negatives recovered by symmetry.
static __device__ __constant__ int S_DY[NSHIFT] = {0,0,1,1,1,1,1,2,2,2,2,2};
static __device__ __constant__ int S_DX[NSHIFT] = {1,2,-2,-1,0,1,2,-2,-1,0,1,2};

// R7 = R6 resubmitted (R6 bench was an infrastructure failure, no data).
// R6 = the measured-best R2 geometry (8-row tiles, 512-thread blocks,
// 2 blocks/CU) with only verified-safe deltas:
//  - stats moved out of k_corr (R2's 256 stats blocks serialized as a tail
//    behind the corr wave — they shared its 42KB LDS footprint) into k_loss.
//  - normalization deferred to k_fin (no fences, no ticket — R4's
//    512 device-scope __threadfence ticket cost ~10us in L2 wb/inv).
//  - NO chunk-fold pass (R5's 13-map fold cost ~8us serial to save ~2us of
//    already-cache-hit loads in k_loss).
#define TROWS  8
#define SROWS  (TROWS + 2)                       // 10 staged rows
#define NTILE  (H / TROWS)                       // 16
#define NCORRB (BATCH * NTILE * NCHUNK)          // 512 corr blocks (2/CU)
#define NLOSSB (NPIX / 256)                      // 512 loss blocks

__device__ __forceinline__ void fma4(float& acc, const float4& a, const float4& b) {
    acc = fmaf(a.x, b.x, acc);
    acc = fmaf(a.y, b.y, acc);
    acc = fmaf(a.z, b.z, acc);
    acc = fmaf(a.w, b.w, acc);
}

// ---------------------------------------------------------------------------
// Kernel C: pure correlation. Grid decode: chunk(4) | tile(16) | b(8).
//   512 thr; each thread computes 2 adjacent output rows (block covers 8
//   rows, stages 10 rows x 4 channels as float4-per-pixel in LDS; 0 bank
//   conflicts measured for this read pattern).
//   Double-buffered LDS: ONE barrier per channel-quad. Depth-2 register
//   prefetch: quad k+2's global loads issue during quad k's compute.
//   Block 0 zeroes the tiny stats globals (stream order -> visible to k_loss).
// __launch_bounds__(512,4): 8 waves/block, 2 blocks/CU, 128-VGPR budget.
// ---------------------------------------------------------------------------
__global__ __launch_bounds__(512, 4) void k_corr(const float* __restrict__ er,
                                                 float* __restrict__ comb,
                                                 int* __restrict__ cnt,
                                                 int* __restrict__ inc,
                                                 float* __restrict__ tot) {
    __shared__ float4 lds[2][SROWS][132];   // 2 buffers, 10 rows, x padded 2/side
    int t = threadIdx.x;

    // block 0: init the tiny globals (consumed only by k_loss/k_fin, later)
    if (blockIdx.x == 0) {
        if (t < 8)               cnt[t] = 0;
        else if (t < 16)         inc[t - 8] = 0;
        else if (t < 24)         tot[t - 16] = 0.0f;
    }

    int blk = blockIdx.x;
    int chunk = blk & 3;
    int tile  = (blk >> 2) & 15;
    int b     = blk >> 6;
    int y0 = tile * TROWS;           // block covers output rows y0..y0+7
    int c0 = chunk * CPC;
    int r = t >> 7;                  // thread handles output rows y0+2r, y0+2r+1
    int x = t & 127;

    // zero the x-pad slots of BOTH buffers once (first barrier makes visible)
    if (t >= 128 && t < 128 + 2 * SROWS * 4) {   // 80 threads, off the init path
        int u = t - 128;
        int bi = u / (SROWS * 4), rem = u % (SROWS * 4);
        int row = rem >> 2, col = rem & 3;
        int xs = (col < 2) ? col : (col + 128);   // 0,1,130,131
        lds[bi][row][xs] = make_float4(0.f, 0.f, 0.f, 0.f);
    }

    float accA[13], accB[13];
#pragma unroll
    for (int i = 0; i < 13; i++) { accA[i] = 0.0f; accB[i] = 0.0f; }

    const float* base = er + (size_t)b * CH * PLANE;

    // prefetch registers: up to 3 stage slots x 4 channels (slot 2: t<256 only;
    // staged px = 10*128 = 1280 = 2.5 * 512)
    float pf[3][4];
    auto load_quad = [&](int c) {
#pragma unroll
        for (int k = 0; k < 3; ++k) {
            if (k < 2 || t < 256) {
                int s = t + k * 512;         // 0..1279
                int row = s >> 7;            // 0..9
                int xs = s & 127;
                int y = y0 + row;
                if (y < H) {
                    const float* p0 = base + (size_t)c * PLANE + y * W + xs;
                    pf[k][0] = p0[0];
                    pf[k][1] = p0[PLANE];
                    pf[k][2] = p0[2 * PLANE];
                    pf[k][3] = p0[3 * PLANE];
                } else {
                    pf[k][0] = 0.f; pf[k][1] = 0.f; pf[k][2] = 0.f; pf[k][3] = 0.f;
                }
            }
        }
    };
    auto commit_quad = [&](int bi) {
#pragma unroll
        for (int k = 0; k < 3; ++k) {
            if (k < 2 || t < 256) {
                int s = t + k * 512;
                int row = s >> 7;
                int xs = s & 127;
                lds[bi][row][xs + 2] = make_float4(pf[k][0], pf[k][1], pf[k][2], pf[k][3]);
            }
        }
    };

    const int iters = CPC / 4;       // 16
    // prologue: quad 0 -> buf0; quad 1 in flight
    load_quad(c0);
    commit_quad(0);
    load_quad(c0 + 4);

    auto iter = [&](int it, int cur) {
        __syncthreads();   // buf[cur] writes visible; buf[cur^1] reads (prev iter) done
        if (it + 1 < iters) commit_quad(cur ^ 1);          // vmcnt wait lands here
        if (it + 2 < iters) load_quad(c0 + 4 * (it + 2));  // overlaps compute below

        const float4* lp = &lds[cur][2 * r][x + 2];
        float4 cA = lp[0];               // (rel row 0, dx 0)
        float4 cB = lp[132];             // (rel row 1, dx 0)
        // rel row 0: dx {0,1,2} -> accA[0..2]
        {
            float4 v1 = lp[1], v2 = lp[2];
            fma4(accA[0], cA, cA);
            fma4(accA[1], cA, v1);
            fma4(accA[2], cA, v2);
        }
        // rel row 1: dx {-2..2} -> accA[3..7]; accB[0..2] (dx 0,1,2)
        {
            float4 m2 = lp[130], m1 = lp[131], p1 = lp[133], p2 = lp[134];
            fma4(accA[3], cA, m2);
            fma4(accA[4], cA, m1);
            fma4(accA[5], cA, cB);
            fma4(accA[6], cA, p1);
            fma4(accA[7], cA, p2);
            fma4(accB[0], cB, cB);
            fma4(accB[1], cB, p1);
            fma4(accB[2], cB, p2);
        }
        // rel row 2: dx {-2..2} -> accA[8..12]; accB[3..7]
        {
            float4 m2 = lp[262], m1 = lp[263], v0 = lp[264], p1 = lp[265], p2 = lp[266];
            fma4(accA[8],  cA, m2);
            fma4(accA[9],  cA, m1);
            fma4(accA[10], cA, v0);
            fma4(accA[11], cA, p1);
            fma4(accA[12], cA, p2);
            fma4(accB[3], cB, m2);
            fma4(accB[4], cB, m1);
            fma4(accB[5], cB, v0);
            fma4(accB[6], cB, p1);
            fma4(accB[7], cB, p2);
        }
        // rel row 3: dx {-2..2} -> accB[8..12]
        {
            float4 m2 = lp[394], m1 = lp[395], v0 = lp[396], p1 = lp[397], p2 = lp[398];
            fma4(accB[8],  cB, m2);
            fma4(accB[9],  cB, m1);
            fma4(accB[10], cB, v0);
            fma4(accB[11], cB, p1);
            fma4(accB[12], cB, p2);
        }
    };

    for (int it = 0; it < iters; it += 2) {
        iter(it, 0);
        iter(it + 1, 1);
    }

    // plain coalesced stores into this chunk's private slice
    float* cb = comb + (size_t)chunk * CSTRIDE;
    int pixA = b * PLANE + (y0 + 2 * r) * W + x;
    int pixB = pixA + W;
#pragma unroll
    for (int m = 0; m < NSHIFT; ++m) {
        cb[m * NPIX + pixA] = accA[m + 1];
        cb[m * NPIX + pixB] = accB[m + 1];
    }
    cb[NSHIFT * NPIX + pixA] = accA[0];
    cb[NSHIFT * NPIX + pixB] = accB[0];
}

// ---------------------------------------------------------------------------
// Kernel R: per-pixel reciprocal norm = 1/max(sqrt(sum_c normsq), 1e-8).
// Small (512 blocks, 2.6 MB traffic) — the R5 13-map fold variant regressed.
// ---------------------------------------------------------------------------
__global__ __launch_bounds__(256) void k_rn(const float* __restrict__ comb,
                                            float* __restrict__ rn) {
    int idx = blockIdx.x * 256 + threadIdx.x;
    const float* ns = comb + NSHIFT * NPIX;
    float s = (ns[idx] + ns[idx + CSTRIDE]) + (ns[idx + 2 * CSTRIDE] + ns[idx + 3 * CSTRIDE]);
    rn[idx] = fminf(rsqrtf(s), 1e8f);   // s==0 -> inf -> clamp = 1/1e-8
}

// ---------------------------------------------------------------------------
// Kernel L: per-valid-pixel loss assembly + per-image stats (raw sums only;
// normalization deferred to k_fin). 4-chunk sum folded at load time (these
// loads are L2/L3-hits and latency-hidden — measured neutral vs pre-folding).
// ---------------------------------------------------------------------------
__device__ __forceinline__ float sum4c(const float* __restrict__ p) {
    return (p[0] + p[CSTRIDE]) + (p[2 * CSTRIDE] + p[3 * CSTRIDE]);
}

__global__ __launch_bounds__(256) void k_loss(const float* __restrict__ comb,
                                              const float* __restrict__ rn,
                                              const int* __restrict__ seg,
                                              const int* __restrict__ gtb,
                                              int* __restrict__ cnt,
                                              int* __restrict__ inc,
                                              float* __restrict__ tot) {
    const float* dots = comb;                  // + i*NPIX per map (chunk 0 slice)
    int idx = blockIdx.x * 256 + threadIdx.x;
    int b = idx >> 14;                         // uniform per block (64 blocks/image)
    int rem = idx & (PLANE - 1);
    int y = rem >> 7;
    int x = rem & 127;

    float val = 0.0f;
    int my_cnt = 0, my_any = 0;
    {
        int sp = seg[idx];
        int gp = gtb[idx];
        int s0 = (sp == 255) ? 0 : sp;
        int g0 = (gp == 255) ? 0 : gp;
        if (s0 > 0 && g0 > 0) {
            my_any = 1;
            if (y >= 2 && y < H - 2 && x >= 2 && x < W - 2) {
                my_cnt = 1;
                float npr = rn[idx];
                float sum = 0.0f;
#pragma unroll
                for (int i = 0; i < NSHIFT; ++i) {
                    int off = S_DY[i] * W + S_DX[i];
                    // + shift: cos(p, p+d)
                    {
                        float d  = sum4c(dots + i * NPIX + idx);
                        float cosv = d * (npr * rn[idx + off]);
                        int sq = seg[idx + off];
                        float lab = (sp == sq && sp < 2) ? 1.0f : 0.0f;
                        float tt = cosv - lab;
                        sum = fmaf(tt, tt, sum);
                    }
                    // - shift: cos(p, p-d) = dot_d(p-d)/(norm(p)norm(p-d))
                    {
                        float d  = sum4c(dots + i * NPIX + idx - off);
                        float cosv = d * (npr * rn[idx - off]);
                        int sq = seg[idx - off];
                        float lab = (sp == sq && sp < 2) ? 1.0f : 0.0f;
                        float tt = cosv - lab;
                        sum = fmaf(tt, tt, sum);
                    }
                }
                val = sum;
            }
        }
    }

    // block reduction: wave shuffle then LDS across 4 waves
    for (int o = 32; o > 0; o >>= 1) {
        val    += __shfl_down(val, o, 64);
        my_cnt += __shfl_down(my_cnt, o, 64);
        my_any |= __shfl_down(my_any, o, 64);
    }
    __shared__ float wsum[4];
    __shared__ int wc[4], wa[4];
    int lane = threadIdx.x & 63;
    int wid  = threadIdx.x >> 6;
    if (lane == 0) { wsum[wid] = val; wc[wid] = my_cnt; wa[wid] = my_any; }
    __syncthreads();
    if (threadIdx.x == 0) {
        float s = wsum[0] + wsum[1] + wsum[2] + wsum[3];
        int c = wc[0] + wc[1] + wc[2] + wc[3];
        int a = wa[0] | wa[1] | wa[2] | wa[3];
        if (s != 0.0f) atomicAdd(&tot[b], s);
        if (c) atomicAdd(&cnt[b], c);
        if (a) atomicOr(&inc[b], 1);
    }
}

// ---------------------------------------------------------------------------
// Kernel F: final normalization (1 block; k_loss's atomics are visible at
// the kernel boundary — no fences needed).
// out = ( sum_b inc_b ? tot_b / (24 * max(cnt_b,1)) : 0 ) / max(sum inc_b, 1)
// ---------------------------------------------------------------------------
__global__ __launch_bounds__(64) void k_fin(const int* __restrict__ cnt,
                                            const int* __restrict__ inc,
                                            const float* __restrict__ tot,
                                            float* __restrict__ out) {
    if (threadIdx.x == 0) {
        int sn = 0;
        float s = 0.0f;
#pragma unroll
        for (int b = 0; b < BATCH; ++b) {
            int ib = inc[b];
            sn += (ib != 0);
            int cb = cnt[b]; if (cb < 1) cb = 1;
            if (ib) s += tot[b] / (24.0f * (float)cb);
        }
        if (sn < 1) sn = 1;
        out[0] = s / (float)sn;
    }
}

// ---------------------------------------------------------------------------
extern "C" void kernel_launch(void* const* d_in, const int* in_sizes, int n_in,
                              void* d_out, int out_size, void* d_ws, size_t ws_size,
                              hipStream_t stream) {
    const float* er  = (const float*)d_in[0];
    const int*   seg = (const int*)d_in[1];
    const int*   gtb = (const int*)d_in[2];
    float* out = (float*)d_out;

    float* ws   = (float*)d_ws;
    float* comb = ws;                                  // 4 * 13 * NPIX floats (27.3 MB)
    float* rn   = comb + NCHUNK * CSTRIDE;             // NPIX floats (0.5 MB)
    float* tot  = rn + NPIX;                           // 8 floats
    int*   cnt  = (int*)(tot + 8);                     // 8 ints
    int*   inc  = cnt + 8;                             // 8 ints

    hipLaunchKernelGGL(k_corr, dim3(NCORRB), dim3(512), 0, stream,
                       er, comb, cnt, inc, tot);
    hipLaunchKernelGGL(k_rn, dim3(NPIX / 256), dim3(256), 0, stream, comb, rn);
    hipLaunchKernelGGL(k_loss, dim3(NLOSSB), dim3(256), 0, stream,
                       comb, rn, seg, gtb, cnt, inc, tot);
    hipLaunchKernelGGL(k_fin, dim3(1), dim3(64), 0, stream, cnt, inc, tot, out);
}